// Round 1
// baseline (1557.137 us; speedup 1.0000x reference)
//
#include <hip/hip_runtime.h>
#include <hip/hip_bf16.h>

// Fused linear-projection + cross-entropy for N=8192, D=2048, V=32000.
// Plan: fp32->bf16 convert (ws) -> 128x128-tile MFMA GEMM with fused
// online-LSE epilogue writing (max,sum) partials per (row, vtile) ->
// per-row combine -> scalar mean. ws requirement ~181 MB.

typedef __bf16 bf16_t;
typedef bf16_t bf16x8 __attribute__((ext_vector_type(8)));
typedef float f32x4 __attribute__((ext_vector_type(4)));

constexpr int N_TOK = 8192;
constexpr int DIM   = 2048;
constexpr int VOCAB = 32000;
constexpr int BM = 128, BN = 128, BK = 64;
constexpr int MT  = N_TOK / BM;   // 64 row tiles
constexpr int NVT = VOCAB / BN;   // 250 vocab tiles
constexpr int IGNORE_INDEX = -100;

#define GPTR(p) ((const __attribute__((address_space(1))) void*)(p))
#define LPTR(p) ((__attribute__((address_space(3))) void*)(p))

__device__ __forceinline__ bf16_t f2bf(float f) {
  union { float f; unsigned u; } in; in.f = f;
  unsigned u = in.u;
  unsigned r = u + 0x7fffu + ((u >> 16) & 1u);   // RNE
  union { unsigned short s; bf16_t b; } out;
  out.s = (unsigned short)(r >> 16);
  return out.b;
}

// ---------------- fp32 -> bf16 convert (8 elems/thread, vectorized) --------
__global__ __launch_bounds__(256) void cvt_f32_bf16(const float* __restrict__ src,
                                                    bf16_t* __restrict__ dst, int n8) {
  int i = blockIdx.x * 256 + threadIdx.x;
  if (i >= n8) return;
  const float4* s = (const float4*)src;
  float4 a = s[2 * (size_t)i], b = s[2 * (size_t)i + 1];
  bf16x8 o;
  o[0] = f2bf(a.x); o[1] = f2bf(a.y); o[2] = f2bf(a.z); o[3] = f2bf(a.w);
  o[4] = f2bf(b.x); o[5] = f2bf(b.y); o[6] = f2bf(b.z); o[7] = f2bf(b.w);
  *(bf16x8*)(dst + (size_t)i * 8) = o;
}

// ---------------- main: GEMM tile + fused LSE partial epilogue -------------
// C[m][v] = sum_k X[m][k] * W[v][k]  (NT GEMM, both operands row-major in K)
// LDS tiles [128][64] bf16 with chunk-XOR swizzle (chunk ^= row&7), staged via
// global_load_lds(16B) with pre-swizzled global source (linear LDS dest).
__global__ __launch_bounds__(256, 2) void fused_gemm_lse(
    const bf16_t* __restrict__ X, const bf16_t* __restrict__ W,
    const int* __restrict__ target,
    float2* __restrict__ partials, float* __restrict__ tgt_logit) {
  __shared__ __align__(16) char smem[2 * BM * BK * 2];  // 32 KB
  bf16_t* As = (bf16_t*)smem;
  bf16_t* Bs = (bf16_t*)(smem + BM * BK * 2);

  const int tid  = threadIdx.x;
  const int lane = tid & 63;
  const int wid  = tid >> 6;
  const int wr   = wid >> 1;   // 2x2 wave grid, each wave 64x64
  const int wc   = wid & 1;
  const int l15  = lane & 15;
  const int lg   = lane >> 4;

  // XCD-bijective swizzle: grid = 16000 = 8 * 2000.
  int bid  = blockIdx.x;
  int wgid = (bid & 7) * 2000 + (bid >> 3);
  int mt = wgid & (MT - 1);   // M fastest: 64 consecutive blocks share W tile
  int vt = wgid >> 6;
  const int brow = mt * BM;
  const int bcol = vt * BN;

  f32x4 acc[4][4];
#pragma unroll
  for (int m = 0; m < 4; ++m)
#pragma unroll
    for (int n = 0; n < 4; ++n)
      acc[m][n] = (f32x4){0.f, 0.f, 0.f, 0.f};

  for (int kt = 0; kt < DIM; kt += BK) {
    // stage 16 KB per matrix: 4 issues x 256 thr x 16B. LDS dest linear,
    // global source chunk-swizzled (sc = cin ^ (row&7)) -> LDS[row][cin]
    // holds k-chunk (cin ^ (row&7)).
#pragma unroll
    for (int it = 0; it < 4; ++it) {
      int c   = it * 256 + tid;   // chunk id, 16B each
      int row = c >> 3;
      int cin = c & 7;
      int sc  = cin ^ (row & 7);
      const bf16_t* ga = X + (size_t)(brow + row) * DIM + kt + sc * 8;
      const bf16_t* gb = W + (size_t)(bcol + row) * DIM + kt + sc * 8;
      __builtin_amdgcn_global_load_lds(GPTR(ga), LPTR(As + c * 8), 16, 0, 0);
      __builtin_amdgcn_global_load_lds(GPTR(gb), LPTR(Bs + c * 8), 16, 0, 0);
    }
    __syncthreads();
#pragma unroll
    for (int ks = 0; ks < 2; ++ks) {
      bf16x8 a[4], b[4];
#pragma unroll
      for (int m = 0; m < 4; ++m) {
        int row = wr * 64 + m * 16 + l15;
        int ch  = (ks * 4 + lg) ^ (row & 7);
        a[m] = *(const bf16x8*)(As + row * BK + ch * 8);
      }
#pragma unroll
      for (int n = 0; n < 4; ++n) {
        int row = wc * 64 + n * 16 + l15;
        int ch  = (ks * 4 + lg) ^ (row & 7);
        b[n] = *(const bf16x8*)(Bs + row * BK + ch * 8);
      }
#pragma unroll
      for (int m = 0; m < 4; ++m)
#pragma unroll
        for (int n = 0; n < 4; ++n)
          acc[m][n] = __builtin_amdgcn_mfma_f32_16x16x32_bf16(a[m], b[n], acc[m][n], 0, 0, 0);
    }
    __syncthreads();
  }

  // ---- fused epilogue: per-row (max, sumexp) over this block's 128 cols ----
  // C/D layout: value acc[m][n][i] of lane l is row (m*16 + lg*4 + i),
  // col (n*16 + l15) within the wave's 64x64 tile.
  float* smax = (float*)smem;            // [128][2]
  float* ssum = (float*)(smem + 1024);   // [128][2]
#pragma unroll
  for (int m = 0; m < 4; ++m) {
#pragma unroll
    for (int i = 0; i < 4; ++i) {
      int rloc = wr * 64 + m * 16 + lg * 4 + i;
      int grow = brow + rloc;
      int tgt  = target[grow];
      float v0 = acc[m][0][i], v1 = acc[m][1][i], v2 = acc[m][2][i], v3 = acc[m][3][i];
      int colbase = bcol + wc * 64 + l15;
      if (colbase      == tgt) tgt_logit[grow] = v0;
      if (colbase + 16 == tgt) tgt_logit[grow] = v1;
      if (colbase + 32 == tgt) tgt_logit[grow] = v2;
      if (colbase + 48 == tgt) tgt_logit[grow] = v3;
      float rmax = fmaxf(fmaxf(v0, v1), fmaxf(v2, v3));
#pragma unroll
      for (int s = 1; s < 16; s <<= 1) rmax = fmaxf(rmax, __shfl_xor(rmax, s));
      float rsum = __expf(v0 - rmax) + __expf(v1 - rmax) +
                   __expf(v2 - rmax) + __expf(v3 - rmax);
#pragma unroll
      for (int s = 1; s < 16; s <<= 1) rsum += __shfl_xor(rsum, s);
      if (l15 == 0) { smax[rloc * 2 + wc] = rmax; ssum[rloc * 2 + wc] = rsum; }
    }
  }
  __syncthreads();
  if (tid < BM) {
    float m0 = smax[tid * 2], m1 = smax[tid * 2 + 1];
    float s0 = ssum[tid * 2], s1 = ssum[tid * 2 + 1];
    float M = fmaxf(m0, m1);
    float S = s0 * __expf(m0 - M) + s1 * __expf(m1 - M);
    partials[(size_t)(brow + tid) * NVT + vt] = make_float2(M, S);
  }
}

// ---------------- per-row LSE combine + loss; 4 rows/block -----------------
__global__ __launch_bounds__(256) void finalize_rows(
    const float2* __restrict__ partials, const float* __restrict__ tgt_logit,
    const int* __restrict__ target, float2* __restrict__ blocksum) {
  int tid = threadIdx.x, lane = tid & 63, w = tid >> 6;
  int row = blockIdx.x * 4 + w;
  float M = -1e30f, S = 0.f;
  for (int i = lane; i < NVT; i += 64) {
    float2 p = partials[(size_t)row * NVT + i];
    float Mn = fmaxf(M, p.x);
    S = S * __expf(M - Mn) + p.y * __expf(p.x - Mn);
    M = Mn;
  }
#pragma unroll
  for (int s = 1; s < 64; s <<= 1) {
    float Mo = __shfl_xor(M, s), So = __shfl_xor(S, s);
    float Mn = fmaxf(M, Mo);
    S = S * __expf(M - Mn) + So * __expf(Mo - Mn);
    M = Mn;
  }
  __shared__ float ls[4], cs[4];
  if (lane == 0) {
    int t = target[row];
    bool valid = (t != IGNORE_INDEX);
    float lse = M + __logf(S);
    ls[w] = valid ? (lse - tgt_logit[row]) : 0.f;
    cs[w] = valid ? 1.f : 0.f;
  }
  __syncthreads();
  if (tid == 0)
    blocksum[blockIdx.x] = make_float2(ls[0] + ls[1] + ls[2] + ls[3],
                                       cs[0] + cs[1] + cs[2] + cs[3]);
}

__global__ __launch_bounds__(256) void finalize_out(
    const float2* __restrict__ blocksum, float* __restrict__ out) {
  int tid = threadIdx.x;
  float s = 0.f, c = 0.f;
  for (int i = tid; i < N_TOK / 4; i += 256) {
    float2 b = blocksum[i];
    s += b.x; c += b.y;
  }
#pragma unroll
  for (int k = 1; k < 64; k <<= 1) { s += __shfl_xor(s, k); c += __shfl_xor(c, k); }
  __shared__ float ss[4], cc[4];
  int w = tid >> 6;
  if ((tid & 63) == 0) { ss[w] = s; cc[w] = c; }
  __syncthreads();
  if (tid == 0) out[0] = (ss[0] + ss[1] + ss[2] + ss[3]) / (cc[0] + cc[1] + cc[2] + cc[3]);
}

extern "C" void kernel_launch(void* const* d_in, const int* in_sizes, int n_in,
                              void* d_out, int out_size, void* d_ws, size_t ws_size,
                              hipStream_t stream) {
  const float* x = (const float*)d_in[0];
  const float* w = (const float*)d_in[1];
  const int* target = (const int*)d_in[2];
  // d_in[3] = num_splits: irrelevant to the math (pure chunking), ignored.
  float* out = (float*)d_out;

  // workspace layout (~181 MB total)
  char* ws = (char*)d_ws;
  size_t off = 0;
  bf16_t* Xbf = (bf16_t*)(ws + off); off += (size_t)N_TOK * DIM * 2;     // 32 MB
  bf16_t* Wbf = (bf16_t*)(ws + off); off += (size_t)VOCAB * DIM * 2;     // 128 MB
  float2* partials = (float2*)(ws + off); off += (size_t)N_TOK * NVT * 8; // 16 MB
  float*  tgtlog   = (float*)(ws + off);  off += (size_t)N_TOK * 4;
  float2* blocksum = (float2*)(ws + off); off += (size_t)(N_TOK / 4) * 8;
  (void)ws_size; (void)in_sizes; (void)n_in; (void)out_size;

  cvt_f32_bf16<<<(N_TOK * DIM / 8) / 256, 256, 0, stream>>>(x, Xbf, N_TOK * DIM / 8);
  cvt_f32_bf16<<<(VOCAB * DIM / 8) / 256, 256, 0, stream>>>(w, Wbf, VOCAB * DIM / 8);
  fused_gemm_lse<<<MT * NVT, 256, 0, stream>>>(Xbf, Wbf, target, partials, tgtlog);
  finalize_rows<<<N_TOK / 4, 256, 0, stream>>>(partials, tgtlog, target, blocksum);
  finalize_out<<<1, 256, 0, stream>>>(blocksum, out);
}

// Round 2
// 1508.291 us; speedup vs baseline: 1.0324x; 1.0324x over previous
//
#include <hip/hip_runtime.h>
#include <hip/hip_bf16.h>

// Fused linear-projection + cross-entropy, N=8192 D=2048 V=32000.
// R2: 256x256-tile 8-phase schedule (T2 swizzle + T3/T4 counted vmcnt + T5
// setprio), 512 thr / 8 waves, LDS 128 KiB dbuf, fused online-LSE epilogue.

typedef __bf16 bf16_t;
typedef bf16_t bf16x8 __attribute__((ext_vector_type(8)));
typedef float f32x4 __attribute__((ext_vector_type(4)));

constexpr int N_TOK = 8192;
constexpr int DIM   = 2048;
constexpr int VOCAB = 32000;
constexpr int BM = 256, BN = 256, BK = 64;
constexpr int MT  = N_TOK / BM;   // 32 row tiles
constexpr int NVT = VOCAB / BN;   // 125 vocab tiles
constexpr int NKT = DIM / BK;     // 32 K tiles
constexpr int IGNORE_INDEX = -100;

#define GPTR(p) ((const __attribute__((address_space(1))) void*)(p))
#define LPTR(p) ((__attribute__((address_space(3))) void*)(p))

__device__ __forceinline__ bf16_t f2bf(float f) {
  union { float f; unsigned u; } in; in.f = f;
  unsigned u = in.u;
  unsigned r = u + 0x7fffu + ((u >> 16) & 1u);   // RNE
  union { unsigned short s; bf16_t b; } out;
  out.s = (unsigned short)(r >> 16);
  return out.b;
}

// ---------------- fp32 -> bf16 convert, both inputs in one launch ---------
constexpr int XN8 = N_TOK * DIM / 8;   // 2,097,152 (divisible by 256)
constexpr int WN8 = VOCAB * DIM / 8;   // 8,192,000

__global__ __launch_bounds__(256) void cvt_both(const float* __restrict__ x,
                                                const float* __restrict__ w,
                                                bf16_t* __restrict__ xb,
                                                bf16_t* __restrict__ wb) {
  int i = blockIdx.x * 256 + threadIdx.x;
  const float* src; bf16_t* dst; int j;
  if (i < XN8) { src = x; dst = xb; j = i; }
  else { j = i - XN8; if (j >= WN8) return; src = w; dst = wb; }
  const float4* s = (const float4*)src;
  float4 a = s[2 * (size_t)j], b = s[2 * (size_t)j + 1];
  bf16x8 o;
  o[0] = f2bf(a.x); o[1] = f2bf(a.y); o[2] = f2bf(a.z); o[3] = f2bf(a.w);
  o[4] = f2bf(b.x); o[5] = f2bf(b.y); o[6] = f2bf(b.z); o[7] = f2bf(b.w);
  *(bf16x8*)(dst + (size_t)j * 8) = o;
}

// ---------------- main: 256^2 8-phase GEMM + fused LSE epilogue -----------
// C[m][v] = sum_k X[m][k]*W[v][k]. LDS per slot: A[256][64] @0, B[256][64]
// @32KB; 2 slots (128 KiB). Half-tile = 128 rows (16 KiB) = 2 loads/thread.
// Swizzle: 16B-chunk index ^= (row&7), applied on global source (linear LDS
// dest for global_load_lds) and on ds_read address (rule #21).
__global__ __launch_bounds__(512, 2) void fused_gemm_lse(
    const bf16_t* __restrict__ X, const bf16_t* __restrict__ W,
    const int* __restrict__ target,
    float2* __restrict__ partials, float* __restrict__ tgt_logit) {
  __shared__ __align__(16) char smem[131072];

  const int tid  = threadIdx.x;
  const int lane = tid & 63;
  const int wid  = tid >> 6;   // 0..7
  const int wr   = wid >> 2;   // 2 wave-rows   (128 M each)
  const int wc   = wid & 3;    // 4 wave-cols   (64 N each)
  const int l15  = lane & 15;
  const int lg   = lane >> 4;

  // XCD-bijective swizzle: grid 4000 = 8 * 500. M-fastest: 32 consecutive
  // wgids share the same W panel (L2-resident 1 MB).
  int bid  = blockIdx.x;
  int wgid = (bid & 7) * (MT * NVT / 8) + (bid >> 3);
  int mt = wgid & (MT - 1);
  int vt = wgid >> 5;
  const int brow = mt * BM;
  const int bcol = vt * BN;

  const bf16_t* Abase = X + (size_t)brow * DIM;
  const bf16_t* Bbase = W + (size_t)bcol * DIM;

  auto stage = [&](const bf16_t* rowbase, int ktile, int ldsoff) {
#pragma unroll
    for (int i = 0; i < 2; ++i) {
      int c = i * 512 + tid;          // 16B chunk id within half-tile
      int row = c >> 3, cin = c & 7;
      int sc = cin ^ (row & 7);       // pre-swizzled global source
      const bf16_t* g = rowbase + (size_t)row * DIM + ktile * BK + sc * 8;
      __builtin_amdgcn_global_load_lds(GPTR(g), LPTR(smem + ldsoff + c * 16), 16, 0, 0);
    }
  };
  auto ldA = [&](int slot, int row, int ks) -> bf16x8 {
    int ch = (ks * 4 + lg) ^ (row & 7);
    return *(const bf16x8*)(smem + slot + row * 128 + ch * 16);
  };
  auto ldB = [&](int slot, int row, int ks) -> bf16x8 {
    int ch = (ks * 4 + lg) ^ (row & 7);
    return *(const bf16x8*)(smem + slot + 32768 + row * 128 + ch * 16);
  };

  f32x4 acc[8][4];
#pragma unroll
  for (int m = 0; m < 8; ++m)
#pragma unroll
    for (int n = 0; n < 4; ++n)
      acc[m][n] = (f32x4){0.f, 0.f, 0.f, 0.f};

  // prologue: tile0 complete + A halves of tile1; retire tile0, keep 4 out.
  stage(Abase,             0, 0);
  stage(Abase + 128 * DIM, 0, 16384);
  stage(Bbase,             0, 32768);
  stage(Bbase + 128 * DIM, 0, 49152);
  stage(Abase,             1, 65536);
  stage(Abase + 128 * DIM, 1, 65536 + 16384);
  asm volatile("s_waitcnt vmcnt(4)" ::: "memory");
  __builtin_amdgcn_s_barrier();

  for (int t = 0; t < NKT; ++t) {
    const int cur = (t & 1) * 65536;
    const int nxt = 65536 - cur;
    const int ktB = (t + 1) & (NKT - 1);   // wrap keeps vmcnt ledger uniform
    const int ktA = (t + 2) & (NKT - 1);

    bf16x8 a0[4][2], a1[4][2], b[4][2];

    // ---- phase 0: read A-low + B(n0,1); stage B0(t+1); MFMA q(m0-3,n0-1)
#pragma unroll
    for (int m = 0; m < 4; ++m)
#pragma unroll
      for (int ks = 0; ks < 2; ++ks)
        a0[m][ks] = ldA(cur, wr * 128 + m * 16 + l15, ks);
#pragma unroll
    for (int n = 0; n < 2; ++n)
#pragma unroll
      for (int ks = 0; ks < 2; ++ks)
        b[n][ks] = ldB(cur, wc * 64 + n * 16 + l15, ks);
    stage(Bbase, ktB, nxt + 32768);
    __builtin_amdgcn_s_barrier();
    __builtin_amdgcn_s_setprio(1);
#pragma unroll
    for (int m = 0; m < 4; ++m)
#pragma unroll
      for (int n = 0; n < 2; ++n)
#pragma unroll
        for (int ks = 0; ks < 2; ++ks)
          acc[m][n] = __builtin_amdgcn_mfma_f32_16x16x32_bf16(a0[m][ks], b[n][ks], acc[m][n], 0, 0, 0);
    __builtin_amdgcn_s_setprio(0);
    __builtin_amdgcn_s_barrier();

    // ---- phase 1: read A-high + B(n2,3); stage B1(t+1); MFMA q(m0-3,n2-3)
#pragma unroll
    for (int m = 0; m < 4; ++m)
#pragma unroll
      for (int ks = 0; ks < 2; ++ks)
        a1[m][ks] = ldA(cur, wr * 128 + 64 + m * 16 + l15, ks);
#pragma unroll
    for (int n = 2; n < 4; ++n)
#pragma unroll
      for (int ks = 0; ks < 2; ++ks)
        b[n][ks] = ldB(cur, wc * 64 + n * 16 + l15, ks);
    stage(Bbase + 128 * DIM, ktB, nxt + 49152);
    __builtin_amdgcn_s_barrier();
    __builtin_amdgcn_s_setprio(1);
#pragma unroll
    for (int m = 0; m < 4; ++m)
#pragma unroll
      for (int n = 2; n < 4; ++n)
#pragma unroll
        for (int ks = 0; ks < 2; ++ks)
          acc[m][n] = __builtin_amdgcn_mfma_f32_16x16x32_bf16(a0[m][ks], b[n][ks], acc[m][n], 0, 0, 0);
    __builtin_amdgcn_s_setprio(0);
    __builtin_amdgcn_s_barrier();
    // all ds_reads of tile t are now globally complete -> slot cur reusable

    // ---- phase 2: stage A0(t+2) into cur; MFMA q(m4-7,n2-3)
    stage(Abase, ktA, cur);
    __builtin_amdgcn_s_barrier();
    __builtin_amdgcn_s_setprio(1);
#pragma unroll
    for (int m = 0; m < 4; ++m)
#pragma unroll
      for (int n = 2; n < 4; ++n)
#pragma unroll
        for (int ks = 0; ks < 2; ++ks)
          acc[m + 4][n] = __builtin_amdgcn_mfma_f32_16x16x32_bf16(a1[m][ks], b[n][ks], acc[m + 4][n], 0, 0, 0);
    __builtin_amdgcn_s_setprio(0);
    __builtin_amdgcn_s_barrier();

    // ---- phase 3: stage A1(t+2); MFMA q(m4-7,n0-1); counted vmcnt(4)
    stage(Abase + 128 * DIM, ktA, cur + 16384);
    __builtin_amdgcn_s_barrier();
    __builtin_amdgcn_s_setprio(1);
#pragma unroll
    for (int m = 0; m < 4; ++m)
#pragma unroll
      for (int n = 0; n < 2; ++n)
#pragma unroll
        for (int ks = 0; ks < 2; ++ks)
          acc[m + 4][n] = __builtin_amdgcn_mfma_f32_16x16x32_bf16(a1[m][ks], b[n][ks], acc[m + 4][n], 0, 0, 0);
    __builtin_amdgcn_s_setprio(0);
    asm volatile("s_waitcnt vmcnt(4)" ::: "memory");   // tile t+1 resident
    __builtin_amdgcn_s_barrier();
  }

  // ---- fused epilogue: per-row (max, sumexp) over this block's 256 cols ---
  __syncthreads();   // drains remaining in-flight stages, frees LDS
  float* smax = (float*)smem;            // [256][4]
  float* ssum = (float*)(smem + 4096);   // [256][4]
#pragma unroll
  for (int m = 0; m < 8; ++m) {
#pragma unroll
    for (int i = 0; i < 4; ++i) {
      int rloc = wr * 128 + m * 16 + lg * 4 + i;
      int grow = brow + rloc;
      int tgt  = target[grow];
      float v0 = acc[m][0][i], v1 = acc[m][1][i], v2 = acc[m][2][i], v3 = acc[m][3][i];
      int colbase = bcol + wc * 64 + l15;
      if (colbase      == tgt) tgt_logit[grow] = v0;
      if (colbase + 16 == tgt) tgt_logit[grow] = v1;
      if (colbase + 32 == tgt) tgt_logit[grow] = v2;
      if (colbase + 48 == tgt) tgt_logit[grow] = v3;
      float rmax = fmaxf(fmaxf(v0, v1), fmaxf(v2, v3));
#pragma unroll
      for (int s = 1; s < 16; s <<= 1) rmax = fmaxf(rmax, __shfl_xor(rmax, s));
      float rsum = __expf(v0 - rmax) + __expf(v1 - rmax) +
                   __expf(v2 - rmax) + __expf(v3 - rmax);
#pragma unroll
      for (int s = 1; s < 16; s <<= 1) rsum += __shfl_xor(rsum, s);
      if (l15 == 0) { smax[rloc * 4 + wc] = rmax; ssum[rloc * 4 + wc] = rsum; }
    }
  }
  __syncthreads();
  if (tid < BM) {
    float M = smax[tid * 4], S = ssum[tid * 4];
#pragma unroll
    for (int c = 1; c < 4; ++c) {
      float m2 = smax[tid * 4 + c], s2 = ssum[tid * 4 + c];
      float Mn = fmaxf(M, m2);
      S = S * __expf(M - Mn) + s2 * __expf(m2 - Mn);
      M = Mn;
    }
    partials[(size_t)(brow + tid) * NVT + vt] = make_float2(M, S);
  }
}

// ---------------- per-row LSE combine + loss; 4 rows/block -----------------
__global__ __launch_bounds__(256) void finalize_rows(
    const float2* __restrict__ partials, const float* __restrict__ tgt_logit,
    const int* __restrict__ target, float2* __restrict__ blocksum) {
  int tid = threadIdx.x, lane = tid & 63, w = tid >> 6;
  int row = blockIdx.x * 4 + w;
  float M = -1e30f, S = 0.f;
  for (int i = lane; i < NVT; i += 64) {
    float2 p = partials[(size_t)row * NVT + i];
    float Mn = fmaxf(M, p.x);
    S = S * __expf(M - Mn) + p.y * __expf(p.x - Mn);
    M = Mn;
  }
#pragma unroll
  for (int s = 1; s < 64; s <<= 1) {
    float Mo = __shfl_xor(M, s), So = __shfl_xor(S, s);
    float Mn = fmaxf(M, Mo);
    S = S * __expf(M - Mn) + So * __expf(Mo - Mn);
    M = Mn;
  }
  __shared__ float ls[4], cs[4];
  if (lane == 0) {
    int t = target[row];
    bool valid = (t != IGNORE_INDEX);
    float lse = M + __logf(S);
    ls[w] = valid ? (lse - tgt_logit[row]) : 0.f;
    cs[w] = valid ? 1.f : 0.f;
  }
  __syncthreads();
  if (tid == 0)
    blocksum[blockIdx.x] = make_float2(ls[0] + ls[1] + ls[2] + ls[3],
                                       cs[0] + cs[1] + cs[2] + cs[3]);
}

__global__ __launch_bounds__(256) void finalize_out(
    const float2* __restrict__ blocksum, float* __restrict__ out) {
  int tid = threadIdx.x;
  float s = 0.f, c = 0.f;
  for (int i = tid; i < N_TOK / 4; i += 256) {
    float2 b = blocksum[i];
    s += b.x; c += b.y;
  }
#pragma unroll
  for (int k = 1; k < 64; k <<= 1) { s += __shfl_xor(s, k); c += __shfl_xor(c, k); }
  __shared__ float ss[4], cc[4];
  int w = tid >> 6;
  if ((tid & 63) == 0) { ss[w] = s; cc[w] = c; }
  __syncthreads();
  if (tid == 0) out[0] = (ss[0] + ss[1] + ss[2] + ss[3]) / (cc[0] + cc[1] + cc[2] + cc[3]);
}

extern "C" void kernel_launch(void* const* d_in, const int* in_sizes, int n_in,
                              void* d_out, int out_size, void* d_ws, size_t ws_size,
                              hipStream_t stream) {
  const float* x = (const float*)d_in[0];
  const float* w = (const float*)d_in[1];
  const int* target = (const int*)d_in[2];
  float* out = (float*)d_out;

  char* ws = (char*)d_ws;
  size_t off = 0;
  bf16_t* Xbf = (bf16_t*)(ws + off); off += (size_t)N_TOK * DIM * 2;      // 32 MB
  bf16_t* Wbf = (bf16_t*)(ws + off); off += (size_t)VOCAB * DIM * 2;      // 128 MB
  float2* partials = (float2*)(ws + off); off += (size_t)N_TOK * NVT * 8; // 8 MB
  float*  tgtlog   = (float*)(ws + off);  off += (size_t)N_TOK * 4;
  float2* blocksum = (float2*)(ws + off); off += (size_t)(N_TOK / 4) * 8;
  (void)ws_size; (void)in_sizes; (void)n_in; (void)out_size;

  int cvt_blocks = (XN8 + WN8 + 255) / 256;
  cvt_both<<<cvt_blocks, 256, 0, stream>>>(x, w, Xbf, Wbf);
  fused_gemm_lse<<<MT * NVT, 512, 0, stream>>>(Xbf, Wbf, target, partials, tgtlog);
  finalize_rows<<<N_TOK / 4, 256, 0, stream>>>(partials, tgtlog, target, blocksum);
  finalize_out<<<1, 256, 0, stream>>>(blocksum, out);
}

// Round 3
// 1485.214 us; speedup vs baseline: 1.0484x; 1.0155x over previous
//
#include <hip/hip_runtime.h>
#include <hip/hip_bf16.h>

// Fused linear-projection + cross-entropy, N=8192 D=2048 V=32000.
// R3: true per-phase interleave (m201 template): every phase = {ds_read
// subtile || 1 half-tile global_load_lds || [vmcnt(4)] -> s_barrier ->
// lgkmcnt(0) -> setprio(1) 16xMFMA setprio(0) -> s_barrier}.

typedef __bf16 bf16_t;
typedef bf16_t bf16x8 __attribute__((ext_vector_type(8)));
typedef float f32x4 __attribute__((ext_vector_type(4)));

constexpr int N_TOK = 8192;
constexpr int DIM   = 2048;
constexpr int VOCAB = 32000;
constexpr int BM = 256, BN = 256, BK = 64;
constexpr int MT  = N_TOK / BM;   // 32 row tiles
constexpr int NVT = VOCAB / BN;   // 125 vocab tiles
constexpr int NKT = DIM / BK;     // 32 K tiles
constexpr int IGNORE_INDEX = -100;

#define GPTR(p) ((const __attribute__((address_space(1))) void*)(p))
#define LPTR(p) ((__attribute__((address_space(3))) void*)(p))

__device__ __forceinline__ bf16_t f2bf(float f) {
  union { float f; unsigned u; } in; in.f = f;
  unsigned u = in.u;
  unsigned r = u + 0x7fffu + ((u >> 16) & 1u);   // RNE
  union { unsigned short s; bf16_t b; } out;
  out.s = (unsigned short)(r >> 16);
  return out.b;
}

// ---------------- fp32 -> bf16 convert, grid-stride ------------------------
constexpr int XN8 = N_TOK * DIM / 8;   // 2,097,152
constexpr int WN8 = VOCAB * DIM / 8;   // 8,192,000
constexpr int CVT_BLOCKS = 2048;

__global__ __launch_bounds__(256) void cvt_both(const float* __restrict__ x,
                                                const float* __restrict__ w,
                                                bf16_t* __restrict__ xb,
                                                bf16_t* __restrict__ wb) {
  for (int i = blockIdx.x * 256 + threadIdx.x; i < XN8 + WN8; i += CVT_BLOCKS * 256) {
    const float* src; bf16_t* dst; int j;
    if (i < XN8) { src = x; dst = xb; j = i; }
    else { src = w; dst = wb; j = i - XN8; }
    const float4* s = (const float4*)src;
    float4 a = s[2 * (size_t)j], b = s[2 * (size_t)j + 1];
    bf16x8 o;
    o[0] = f2bf(a.x); o[1] = f2bf(a.y); o[2] = f2bf(a.z); o[3] = f2bf(a.w);
    o[4] = f2bf(b.x); o[5] = f2bf(b.y); o[6] = f2bf(b.z); o[7] = f2bf(b.w);
    *(bf16x8*)(dst + (size_t)j * 8) = o;
  }
}

// ---------------- GEMM helpers --------------------------------------------
// LDS slot map (slot in {0, 65536}): A rows 0..255 @ slot + row*128 (A-low
// 16KB, A-high 16KB contiguous), B rows @ slot + 32768 + row*128.
// Swizzle: 16B-chunk ^= (row&7) on global source AND on ds_read (rule #21).
__device__ __forceinline__ void stage_half(const bf16_t* rowbase, int ktile,
                                           char* smem, int ldsoff, int tid) {
#pragma unroll
  for (int i = 0; i < 2; ++i) {
    int c = i * 512 + tid;          // 16B chunk id within 128-row half-tile
    int row = c >> 3, cin = c & 7;
    int sc = cin ^ (row & 7);
    const bf16_t* g = rowbase + (size_t)row * DIM + ktile * BK + sc * 8;
    __builtin_amdgcn_global_load_lds(GPTR(g), LPTR(smem + ldsoff + c * 16), 16, 0, 0);
  }
}

template <int SLOT>
__device__ __forceinline__ bf16x8 ldA(const char* smem, int row, int ks, int lg) {
  int ch = (ks * 4 + lg) ^ (row & 7);
  return *(const bf16x8*)(smem + SLOT + row * 128 + ch * 16);
}
template <int SLOT>
__device__ __forceinline__ bf16x8 ldB(const char* smem, int row, int ks, int lg) {
  int ch = (ks * 4 + lg) ^ (row & 7);
  return *(const bf16x8*)(smem + SLOT + 32768 + row * 128 + ch * 16);
}

#define MFMA_Q(AVEC, BVEC, MOFF, NOFF)                                          \
  __builtin_amdgcn_s_setprio(1);                                                \
  _Pragma("unroll") for (int ks = 0; ks < 2; ++ks)                              \
    _Pragma("unroll") for (int m = 0; m < 4; ++m)                               \
      _Pragma("unroll") for (int n = 0; n < 2; ++n)                             \
        acc[m + MOFF][n + NOFF] = __builtin_amdgcn_mfma_f32_16x16x32_bf16(      \
            AVEC[m][ks], BVEC[n][ks], acc[m + MOFF][n + NOFF], 0, 0, 0);        \
  __builtin_amdgcn_s_setprio(0);

#define PRE_MFMA()                                    \
  __builtin_amdgcn_s_barrier();                       \
  asm volatile("s_waitcnt lgkmcnt(0)" ::: "memory");

// One K-tile = 4 phases. CUR/NXT are compile-time LDS slot offsets.
template <int CUR, int NXT>
__device__ __forceinline__ void tile_body(
    int ktB, int ktA, const bf16_t* Abase, const bf16_t* Bbase, char* smem,
    int tid, int wr, int wc, int l15, int lg,
    bf16x8 (&alo)[4][2], bf16x8 (&ahi)[4][2],
    bf16x8 (&b01)[2][2], bf16x8 (&b23)[2][2], f32x4 (&acc)[8][4]) {
  // ---- ph0: read alo+b01(t) | stage B0(t+1) | vmcnt(4) | MFMA alo x b01
#pragma unroll
  for (int m = 0; m < 4; ++m)
#pragma unroll
    for (int ks = 0; ks < 2; ++ks)
      alo[m][ks] = ldA<CUR>(smem, wr * 128 + m * 16 + l15, ks, lg);
#pragma unroll
  for (int n = 0; n < 2; ++n)
#pragma unroll
    for (int ks = 0; ks < 2; ++ks)
      b01[n][ks] = ldB<CUR>(smem, wc * 64 + n * 16 + l15, ks, lg);
  stage_half(Bbase, ktB, smem, NXT + 32768, tid);
  asm volatile("s_waitcnt vmcnt(4)" ::: "memory");
  PRE_MFMA();
  MFMA_Q(alo, b01, 0, 0);
  __builtin_amdgcn_s_barrier();

  // ---- ph1: read ahi(t) | stage B1(t+1) | MFMA ahi x b01
#pragma unroll
  for (int m = 0; m < 4; ++m)
#pragma unroll
    for (int ks = 0; ks < 2; ++ks)
      ahi[m][ks] = ldA<CUR>(smem, wr * 128 + 64 + m * 16 + l15, ks, lg);
  stage_half(Bbase + 128 * DIM, ktB, smem, NXT + 49152, tid);
  PRE_MFMA();
  MFMA_Q(ahi, b01, 4, 0);
  __builtin_amdgcn_s_barrier();

  // ---- ph2: read b23(t) | stage A0(t+2) | vmcnt(4) | MFMA ahi x b23
#pragma unroll
  for (int n = 0; n < 2; ++n)
#pragma unroll
    for (int ks = 0; ks < 2; ++ks)
      b23[n][ks] = ldB<CUR>(smem, wc * 64 + (n + 2) * 16 + l15, ks, lg);
  stage_half(Abase, ktA, smem, CUR, tid);
  asm volatile("s_waitcnt vmcnt(4)" ::: "memory");
  PRE_MFMA();
  MFMA_Q(ahi, b23, 4, 2);
  __builtin_amdgcn_s_barrier();

  // ---- ph3: stage A1(t+2) | MFMA alo x b23
  stage_half(Abase + 128 * DIM, ktA, smem, CUR + 16384, tid);
  PRE_MFMA();
  MFMA_Q(alo, b23, 0, 2);
  __builtin_amdgcn_s_barrier();
}

// ---------------- main: 256^2 per-phase-interleaved GEMM + fused LSE ------
__global__ __launch_bounds__(512, 2) void fused_gemm_lse(
    const bf16_t* __restrict__ X, const bf16_t* __restrict__ W,
    const int* __restrict__ target,
    float2* __restrict__ partials, float* __restrict__ tgt_logit) {
  __shared__ __align__(16) char smem[131072];

  const int tid  = threadIdx.x;
  const int lane = tid & 63;
  const int wid  = tid >> 6;
  const int wr   = wid >> 2;   // 2 wave-rows (128 M each)
  const int wc   = wid & 3;    // 4 wave-cols (64 N each)
  const int l15  = lane & 15;
  const int lg   = lane >> 4;

  // XCD-bijective swizzle (grid 4000 = 8*500); M-fastest so one XCD's 32
  // concurrent blocks share one 1 MB W panel in its L2.
  int bid  = blockIdx.x;
  int wgid = (bid & 7) * (MT * NVT / 8) + (bid >> 3);
  int mt = wgid & (MT - 1);
  int vt = wgid >> 5;
  const int brow = mt * BM;
  const int bcol = vt * BN;

  const bf16_t* Abase = X + (size_t)brow * DIM;
  const bf16_t* Bbase = W + (size_t)bcol * DIM;

  f32x4 acc[8][4];
#pragma unroll
  for (int m = 0; m < 8; ++m)
#pragma unroll
    for (int n = 0; n < 4; ++n)
      acc[m][n] = (f32x4){0.f, 0.f, 0.f, 0.f};
  bf16x8 alo[4][2], ahi[4][2], b01[2][2], b23[2][2];

  // prologue: tile0 (4 half-tiles) + A halves of tile1; retire tile0.
  stage_half(Abase,             0, smem, 0,             tid);
  stage_half(Abase + 128 * DIM, 0, smem, 16384,         tid);
  stage_half(Bbase,             0, smem, 32768,         tid);
  stage_half(Bbase + 128 * DIM, 0, smem, 49152,         tid);
  stage_half(Abase,             1, smem, 65536,         tid);
  stage_half(Abase + 128 * DIM, 1, smem, 65536 + 16384, tid);
  asm volatile("s_waitcnt vmcnt(4)" ::: "memory");
  __builtin_amdgcn_s_barrier();

  for (int t = 0; t < NKT; t += 2) {
    tile_body<0, 65536>((t + 1) & (NKT - 1), (t + 2) & (NKT - 1),
                        Abase, Bbase, smem, tid, wr, wc, l15, lg,
                        alo, ahi, b01, b23, acc);
    tile_body<65536, 0>((t + 2) & (NKT - 1), (t + 3) & (NKT - 1),
                        Abase, Bbase, smem, tid, wr, wc, l15, lg,
                        alo, ahi, b01, b23, acc);
  }

  // ---- fused epilogue: per-row (max,sumexp) over this block's 256 cols ----
  __syncthreads();   // drains in-flight wrap stages, frees LDS
  float* smax = (float*)smem;            // [256][4]
  float* ssum = (float*)(smem + 4096);   // [256][4]
#pragma unroll
  for (int m = 0; m < 8; ++m) {
#pragma unroll
    for (int i = 0; i < 4; ++i) {
      int rloc = wr * 128 + m * 16 + lg * 4 + i;
      int grow = brow + rloc;
      int tgt  = target[grow];
      float v0 = acc[m][0][i], v1 = acc[m][1][i], v2 = acc[m][2][i], v3 = acc[m][3][i];
      int colbase = bcol + wc * 64 + l15;
      if (colbase      == tgt) tgt_logit[grow] = v0;
      if (colbase + 16 == tgt) tgt_logit[grow] = v1;
      if (colbase + 32 == tgt) tgt_logit[grow] = v2;
      if (colbase + 48 == tgt) tgt_logit[grow] = v3;
      float rmax = fmaxf(fmaxf(v0, v1), fmaxf(v2, v3));
#pragma unroll
      for (int s = 1; s < 16; s <<= 1) rmax = fmaxf(rmax, __shfl_xor(rmax, s));
      float rsum = __expf(v0 - rmax) + __expf(v1 - rmax) +
                   __expf(v2 - rmax) + __expf(v3 - rmax);
#pragma unroll
      for (int s = 1; s < 16; s <<= 1) rsum += __shfl_xor(rsum, s);
      if (l15 == 0) { smax[rloc * 4 + wc] = rmax; ssum[rloc * 4 + wc] = rsum; }
    }
  }
  __syncthreads();
  if (tid < BM) {
    float M = smax[tid * 4], S = ssum[tid * 4];
#pragma unroll
    for (int c = 1; c < 4; ++c) {
      float m2 = smax[tid * 4 + c], s2 = ssum[tid * 4 + c];
      float Mn = fmaxf(M, m2);
      S = S * __expf(M - Mn) + s2 * __expf(m2 - Mn);
      M = Mn;
    }
    partials[(size_t)(brow + tid) * NVT + vt] = make_float2(M, S);
  }
}

// ---------------- per-row LSE combine + loss; 4 rows/block -----------------
__global__ __launch_bounds__(256) void finalize_rows(
    const float2* __restrict__ partials, const float* __restrict__ tgt_logit,
    const int* __restrict__ target, float2* __restrict__ blocksum) {
  int tid = threadIdx.x, lane = tid & 63, w = tid >> 6;
  int row = blockIdx.x * 4 + w;
  float M = -1e30f, S = 0.f;
  for (int i = lane; i < NVT; i += 64) {
    float2 p = partials[(size_t)row * NVT + i];
    float Mn = fmaxf(M, p.x);
    S = S * __expf(M - Mn) + p.y * __expf(p.x - Mn);
    M = Mn;
  }
#pragma unroll
  for (int s = 1; s < 64; s <<= 1) {
    float Mo = __shfl_xor(M, s), So = __shfl_xor(S, s);
    float Mn = fmaxf(M, Mo);
    S = S * __expf(M - Mn) + So * __expf(Mo - Mn);
    M = Mn;
  }
  __shared__ float ls[4], cs[4];
  if (lane == 0) {
    int t = target[row];
    bool valid = (t != IGNORE_INDEX);
    float lse = M + __logf(S);
    ls[w] = valid ? (lse - tgt_logit[row]) : 0.f;
    cs[w] = valid ? 1.f : 0.f;
  }
  __syncthreads();
  if (tid == 0)
    blocksum[blockIdx.x] = make_float2(ls[0] + ls[1] + ls[2] + ls[3],
                                       cs[0] + cs[1] + cs[2] + cs[3]);
}

__global__ __launch_bounds__(256) void finalize_out(
    const float2* __restrict__ blocksum, float* __restrict__ out) {
  int tid = threadIdx.x;
  float s = 0.f, c = 0.f;
  for (int i = tid; i < N_TOK / 4; i += 256) {
    float2 b = blocksum[i];
    s += b.x; c += b.y;
  }
#pragma unroll
  for (int k = 1; k < 64; k <<= 1) { s += __shfl_xor(s, k); c += __shfl_xor(c, k); }
  __shared__ float ss[4], cc[4];
  int w = tid >> 6;
  if ((tid & 63) == 0) { ss[w] = s; cc[w] = c; }
  __syncthreads();
  if (tid == 0) out[0] = (ss[0] + ss[1] + ss[2] + ss[3]) / (cc[0] + cc[1] + cc[2] + cc[3]);
}

extern "C" void kernel_launch(void* const* d_in, const int* in_sizes, int n_in,
                              void* d_out, int out_size, void* d_ws, size_t ws_size,
                              hipStream_t stream) {
  const float* x = (const float*)d_in[0];
  const float* w = (const float*)d_in[1];
  const int* target = (const int*)d_in[2];
  float* out = (float*)d_out;

  char* ws = (char*)d_ws;
  size_t off = 0;
  bf16_t* Xbf = (bf16_t*)(ws + off); off += (size_t)N_TOK * DIM * 2;      // 32 MB
  bf16_t* Wbf = (bf16_t*)(ws + off); off += (size_t)VOCAB * DIM * 2;      // 128 MB
  float2* partials = (float2*)(ws + off); off += (size_t)N_TOK * NVT * 8; // 8 MB
  float*  tgtlog   = (float*)(ws + off);  off += (size_t)N_TOK * 4;
  float2* blocksum = (float2*)(ws + off); off += (size_t)(N_TOK / 4) * 8;
  (void)ws_size; (void)in_sizes; (void)n_in; (void)out_size;

  cvt_both<<<CVT_BLOCKS, 256, 0, stream>>>(x, w, Xbf, Wbf);
  fused_gemm_lse<<<MT * NVT, 512, 0, stream>>>(Xbf, Wbf, target, partials, tgtlog);
  finalize_rows<<<N_TOK / 4, 256, 0, stream>>>(partials, tgtlog, target, blocksum);
  finalize_out<<<1, 256, 0, stream>>>(blocksum, out);
}

// Round 5
// 1440.782 us; speedup vs baseline: 1.0808x; 1.0308x over previous
//
#include <hip/hip_runtime.h>
#include <hip/hip_bf16.h>

// Fused linear-projection + cross-entropy, N=8192 D=2048 V=32000.
// R5: R4's k-major balanced phases (reads 8/4/8/4, 16 MFMA/phase) hardened:
// sched_barrier(0) after every inline waitcnt (rule #18) + full-drain
// prologue (vmcnt(0)) to remove first-tile exposure. Ledger: outstanding
// {A1(t),A0(t+1)} at tile entry; vmcnt(4)@ph0 retires A1(t); vmcnt(4)@ph3
// retires {A0(t+1),B0(t+1),B1(t+1)}; never 0 mid-loop.

typedef __bf16 bf16_t;
typedef bf16_t bf16x8 __attribute__((ext_vector_type(8)));
typedef float f32x4 __attribute__((ext_vector_type(4)));

constexpr int N_TOK = 8192;
constexpr int DIM   = 2048;
constexpr int VOCAB = 32000;
constexpr int BM = 256, BN = 256, BK = 64;
constexpr int MT  = N_TOK / BM;   // 32 row tiles
constexpr int NVT = VOCAB / BN;   // 125 vocab tiles
constexpr int NKT = DIM / BK;     // 32 K tiles
constexpr int IGNORE_INDEX = -100;

#define GPTR(p) ((const __attribute__((address_space(1))) void*)(p))
#define LPTR(p) ((__attribute__((address_space(3))) void*)(p))

#define VMCNT(N)                                            \
  asm volatile("s_waitcnt vmcnt(" #N ")" ::: "memory");     \
  __builtin_amdgcn_sched_barrier(0)
#define LGKM0()                                             \
  asm volatile("s_waitcnt lgkmcnt(0)" ::: "memory");        \
  __builtin_amdgcn_sched_barrier(0)

__device__ __forceinline__ bf16_t f2bf(float f) {
  union { float f; unsigned u; } in; in.f = f;
  unsigned u = in.u;
  unsigned r = u + 0x7fffu + ((u >> 16) & 1u);   // RNE
  union { unsigned short s; bf16_t b; } out;
  out.s = (unsigned short)(r >> 16);
  return out.b;
}

// ---------------- fp32 -> bf16 convert, grid-stride ------------------------
constexpr int XN8 = N_TOK * DIM / 8;   // 2,097,152
constexpr int WN8 = VOCAB * DIM / 8;   // 8,192,000
constexpr int CVT_BLOCKS = 2048;

__global__ __launch_bounds__(256) void cvt_both(const float* __restrict__ x,
                                                const float* __restrict__ w,
                                                bf16_t* __restrict__ xb,
                                                bf16_t* __restrict__ wb) {
  for (int i = blockIdx.x * 256 + threadIdx.x; i < XN8 + WN8; i += CVT_BLOCKS * 256) {
    const float* src; bf16_t* dst; int j;
    if (i < XN8) { src = x; dst = xb; j = i; }
    else { src = w; dst = wb; j = i - XN8; }
    const float4* s = (const float4*)src;
    float4 a = s[2 * (size_t)j], b = s[2 * (size_t)j + 1];
    bf16x8 o;
    o[0] = f2bf(a.x); o[1] = f2bf(a.y); o[2] = f2bf(a.z); o[3] = f2bf(a.w);
    o[4] = f2bf(b.x); o[5] = f2bf(b.y); o[6] = f2bf(b.z); o[7] = f2bf(b.w);
    *(bf16x8*)(dst + (size_t)j * 8) = o;
  }
}

// ---------------- GEMM helpers --------------------------------------------
// LDS slot map (slot in {0,65536}): A-low rows 0..127 @slot, A-high @slot
// +16384, B rows 0..255 @slot+32768. Swizzle: 16B-chunk ^= (row&7) on the
// global source (linear LDS dest) AND on the ds_read address (rule #21).
__device__ __forceinline__ void stage_half(const bf16_t* base, int kt,
                                           long toff, char* smem, int ldsoff,
                                           int tid) {
  const bf16_t* g = base + kt * BK + toff;
  __builtin_amdgcn_global_load_lds(GPTR(g), LPTR(smem + ldsoff + tid * 16), 16, 0, 0);
  __builtin_amdgcn_global_load_lds(GPTR(g + 64 * DIM), LPTR(smem + ldsoff + 8192 + tid * 16), 16, 0, 0);
}

template <int SLOT>
__device__ __forceinline__ bf16x8 ldA(const char* smem, int row, int ks, int lg) {
  int ch = (ks * 4 + lg) ^ (row & 7);
  return *(const bf16x8*)(smem + SLOT + row * 128 + ch * 16);
}
template <int SLOT>
__device__ __forceinline__ bf16x8 ldB(const char* smem, int row, int ks, int lg) {
  int ch = (ks * 4 + lg) ^ (row & 7);
  return *(const bf16x8*)(smem + SLOT + 32768 + row * 128 + ch * 16);
}

#define PRE_MFMA()                                    \
  __builtin_amdgcn_s_barrier();                       \
  LGKM0();

#define MFMA_HALF(MOFF)                                                         \
  __builtin_amdgcn_s_setprio(1);                                                \
  _Pragma("unroll") for (int m = 0; m < 4; ++m)                                 \
    _Pragma("unroll") for (int n = 0; n < 4; ++n)                               \
      acc[m + MOFF][n] = __builtin_amdgcn_mfma_f32_16x16x32_bf16(               \
          aq[m], bq[n], acc[m + MOFF][n], 0, 0, 0);                             \
  __builtin_amdgcn_s_setprio(0);

// One K-tile = 4 k-major phases. CUR/NXT compile-time LDS slot offsets.
// Stage rotation: ph0 B0(t+1), ph1 B1(t+1), ph2 A1(t+1) -> NXT;
// ph3 A0(t+2) -> CUR (A-low region dead after ph2). vmcnt(4) at ph0/ph3.
template <int CUR, int NXT>
__device__ __forceinline__ void tile_body(
    const bf16_t* Ab, const bf16_t* Bb, int ktB, int ktA2, long toff,
    char* smem, int tid, int wr, int wc, int l15, int lg, f32x4 (&acc)[8][4]) {
  bf16x8 aq[4], bq[4];
  const int arow = wr * 128 + l15;
  const int brow = wc * 64 + l15;

  // ---- ph0: read alo-ks0 + b-ks0 | stage B0(t+1) | vmcnt(4) | MFMA m0-3 ks0
#pragma unroll
  for (int m = 0; m < 4; ++m) aq[m] = ldA<CUR>(smem, arow + m * 16, 0, lg);
#pragma unroll
  for (int n = 0; n < 4; ++n) bq[n] = ldB<CUR>(smem, brow + n * 16, 0, lg);
  stage_half(Bb, ktB, toff, smem, NXT + 32768, tid);
  VMCNT(4);
  PRE_MFMA();
  MFMA_HALF(0);
  __builtin_amdgcn_s_barrier();

  // ---- ph1: read ahi-ks0 | stage B1(t+1) | MFMA m4-7 ks0
#pragma unroll
  for (int m = 0; m < 4; ++m) aq[m] = ldA<CUR>(smem, arow + 64 + m * 16, 0, lg);
  stage_half(Bb + 128 * DIM, ktB, toff, smem, NXT + 49152, tid);
  PRE_MFMA();
  MFMA_HALF(4);
  __builtin_amdgcn_s_barrier();

  // ---- ph2: read alo-ks1 + b-ks1 | stage A1(t+1) | MFMA m0-3 ks1
#pragma unroll
  for (int m = 0; m < 4; ++m) aq[m] = ldA<CUR>(smem, arow + m * 16, 1, lg);
#pragma unroll
  for (int n = 0; n < 4; ++n) bq[n] = ldB<CUR>(smem, brow + n * 16, 1, lg);
  stage_half(Ab + 128 * DIM, ktB, toff, smem, NXT + 16384, tid);
  PRE_MFMA();
  MFMA_HALF(0);
  __builtin_amdgcn_s_barrier();

  // ---- ph3: read ahi-ks1 | stage A0(t+2) -> CUR | vmcnt(4) | MFMA m4-7 ks1
#pragma unroll
  for (int m = 0; m < 4; ++m) aq[m] = ldA<CUR>(smem, arow + 64 + m * 16, 1, lg);
  stage_half(Ab, ktA2, toff, smem, CUR, tid);
  VMCNT(4);
  PRE_MFMA();
  MFMA_HALF(4);
  __builtin_amdgcn_s_barrier();
}

// ---------------- main: 256^2 k-major-phase GEMM + fused LSE --------------
__global__ __launch_bounds__(512, 2) void fused_gemm_lse(
    const bf16_t* __restrict__ X, const bf16_t* __restrict__ W,
    const int* __restrict__ target,
    float2* __restrict__ partials, float* __restrict__ tgt_logit) {
  __shared__ __align__(16) char smem[131072];

  const int tid  = threadIdx.x;
  const int lane = tid & 63;
  const int wid  = tid >> 6;
  const int wr   = wid >> 2;   // 2 wave-rows (128 M each)
  const int wc   = wid & 3;    // 4 wave-cols (64 N each)
  const int l15  = lane & 15;
  const int lg   = lane >> 4;

  // XCD-bijective swizzle (grid 4000 = 8*500); M-fastest: one XCD's 32
  // concurrent blocks share one 1 MB W panel in its L2.
  int bid  = blockIdx.x;
  int wgid = (bid & 7) * (MT * NVT / 8) + (bid >> 3);
  int mt = wgid & (MT - 1);
  int vt = wgid >> 5;
  const int brow = mt * BM;
  const int bcol = vt * BN;

  const bf16_t* Abase = X + (size_t)brow * DIM;
  const bf16_t* Bbase = W + (size_t)bcol * DIM;

  // per-thread stage offset (elements): row = tid>>3, chunk = (tid&7)^(row&7)
  const int srow = tid >> 3;
  const int ssc  = (tid & 7) ^ (srow & 7);
  const long toff = (long)srow * DIM + ssc * 8;

  f32x4 acc[8][4];
#pragma unroll
  for (int m = 0; m < 8; ++m)
#pragma unroll
    for (int n = 0; n < 4; ++n)
      acc[m][n] = (f32x4){0.f, 0.f, 0.f, 0.f};

  // prologue: tile0 all 4 halves + A0(1); FULL drain (first-tile safety).
  stage_half(Abase,             0, toff, smem, 0,     tid);
  stage_half(Abase + 128 * DIM, 0, toff, smem, 16384, tid);
  stage_half(Bbase,             0, toff, smem, 32768, tid);
  stage_half(Bbase + 128 * DIM, 0, toff, smem, 49152, tid);
  stage_half(Abase,             1, toff, smem, 65536, tid);
  VMCNT(0);
  __builtin_amdgcn_s_barrier();

  for (int t = 0; t < NKT; t += 2) {
    tile_body<0, 65536>(Abase, Bbase, (t + 1) & (NKT - 1), (t + 2) & (NKT - 1),
                        toff, smem, tid, wr, wc, l15, lg, acc);
    tile_body<65536, 0>(Abase, Bbase, (t + 2) & (NKT - 1), (t + 3) & (NKT - 1),
                        toff, smem, tid, wr, wc, l15, lg, acc);
  }

  // ---- fused epilogue: per-row (max,sumexp) over this block's 256 cols ----
  __syncthreads();   // drains in-flight wrap stages, frees LDS
  float* smax = (float*)smem;            // [256][4]
  float* ssum = (float*)(smem + 4096);   // [256][4]
#pragma unroll
  for (int m = 0; m < 8; ++m) {
#pragma unroll
    for (int i = 0; i < 4; ++i) {
      int rloc = wr * 128 + m * 16 + lg * 4 + i;
      int grow = brow + rloc;
      int tgt  = target[grow];
      float v0 = acc[m][0][i], v1 = acc[m][1][i], v2 = acc[m][2][i], v3 = acc[m][3][i];
      int colbase = bcol + wc * 64 + l15;
      if (colbase      == tgt) tgt_logit[grow] = v0;
      if (colbase + 16 == tgt) tgt_logit[grow] = v1;
      if (colbase + 32 == tgt) tgt_logit[grow] = v2;
      if (colbase + 48 == tgt) tgt_logit[grow] = v3;
      float rmax = fmaxf(fmaxf(v0, v1), fmaxf(v2, v3));
#pragma unroll
      for (int s = 1; s < 16; s <<= 1) rmax = fmaxf(rmax, __shfl_xor(rmax, s));
      float rsum = __expf(v0 - rmax) + __expf(v1 - rmax) +
                   __expf(v2 - rmax) + __expf(v3 - rmax);
#pragma unroll
      for (int s = 1; s < 16; s <<= 1) rsum += __shfl_xor(rsum, s);
      if (l15 == 0) { smax[rloc * 4 + wc] = rmax; ssum[rloc * 4 + wc] = rsum; }
    }
  }
  __syncthreads();
  if (tid < BM) {
    float M = smax[tid * 4], S = ssum[tid * 4];
#pragma unroll
    for (int c = 1; c < 4; ++c) {
      float m2 = smax[tid * 4 + c], s2 = ssum[tid * 4 + c];
      float Mn = fmaxf(M, m2);
      S = S * __expf(M - Mn) + s2 * __expf(m2 - Mn);
      M = Mn;
    }
    partials[(size_t)(brow + tid) * NVT + vt] = make_float2(M, S);
  }
}

// ---------------- per-row LSE combine + loss; 4 rows/block -----------------
__global__ __launch_bounds__(256) void finalize_rows(
    const float2* __restrict__ partials, const float* __restrict__ tgt_logit,
    const int* __restrict__ target, float2* __restrict__ blocksum) {
  int tid = threadIdx.x, lane = tid & 63, w = tid >> 6;
  int row = blockIdx.x * 4 + w;
  float M = -1e30f, S = 0.f;
  for (int i = lane; i < NVT; i += 64) {
    float2 p = partials[(size_t)row * NVT + i];
    float Mn = fmaxf(M, p.x);
    S = S * __expf(M - Mn) + p.y * __expf(p.x - Mn);
    M = Mn;
  }
#pragma unroll
  for (int s = 1; s < 64; s <<= 1) {
    float Mo = __shfl_xor(M, s), So = __shfl_xor(S, s);
    float Mn = fmaxf(M, Mo);
    S = S * __expf(M - Mn) + So * __expf(Mo - Mn);
    M = Mn;
  }
  __shared__ float ls[4], cs[4];
  if (lane == 0) {
    int t = target[row];
    bool valid = (t != IGNORE_INDEX);
    float lse = M + __logf(S);
    ls[w] = valid ? (lse - tgt_logit[row]) : 0.f;
    cs[w] = valid ? 1.f : 0.f;
  }
  __syncthreads();
  if (tid == 0)
    blocksum[blockIdx.x] = make_float2(ls[0] + ls[1] + ls[2] + ls[3],
                                       cs[0] + cs[1] + cs[2] + cs[3]);
}

__global__ __launch_bounds__(256) void finalize_out(
    const float2* __restrict__ blocksum, float* __restrict__ out) {
  int tid = threadIdx.x;
  float s = 0.f, c = 0.f;
  for (int i = tid; i < N_TOK / 4; i += 256) {
    float2 b = blocksum[i];
    s += b.x; c += b.y;
  }
#pragma unroll
  for (int k = 1; k < 64; k <<= 1) { s += __shfl_xor(s, k); c += __shfl_xor(c, k); }
  __shared__ float ss[4], cc[4];
  int w = tid >> 6;
  if ((tid & 63) == 0) { ss[w] = s; cc[w] = c; }
  __syncthreads();
  if (tid == 0) out[0] = (ss[0] + ss[1] + ss[2] + ss[3]) / (cc[0] + cc[1] + cc[2] + cc[3]);
}

extern "C" void kernel_launch(void* const* d_in, const int* in_sizes, int n_in,
                              void* d_out, int out_size, void* d_ws, size_t ws_size,
                              hipStream_t stream) {
  const float* x = (const float*)d_in[0];
  const float* w = (const float*)d_in[1];
  const int* target = (const int*)d_in[2];
  float* out = (float*)d_out;

  char* ws = (char*)d_ws;
  size_t off = 0;
  bf16_t* Xbf = (bf16_t*)(ws + off); off += (size_t)N_TOK * DIM * 2;      // 32 MB
  bf16_t* Wbf = (bf16_t*)(ws + off); off += (size_t)VOCAB * DIM * 2;      // 128 MB
  float2* partials = (float2*)(ws + off); off += (size_t)N_TOK * NVT * 8; // 8 MB
  float*  tgtlog   = (float*)(ws + off);  off += (size_t)N_TOK * 4;
  float2* blocksum = (float2*)(ws + off); off += (size_t)(N_TOK / 4) * 8;
  (void)ws_size; (void)in_sizes; (void)n_in; (void)out_size;

  cvt_both<<<CVT_BLOCKS, 256, 0, stream>>>(x, w, Xbf, Wbf);
  fused_gemm_lse<<<MT * NVT, 512, 0, stream>>>(Xbf, Wbf, target, partials, tgtlog);
  finalize_rows<<<N_TOK / 4, 256, 0, stream>>>(partials, tgtlog, target, blocksum);
  finalize_out<<<1, 256, 0, stream>>>(blocksum, out);
}